// Round 3
// baseline (174.550 us; speedup 1.0000x reference)
//
#include <hip/hip_runtime.h>
#include <float.h>

// ROI max-pooling. One wave per (batch, roi, output-row i).
// Wave streams rows y in [ys,ye) across the full ROI width, maxing each
// pixel into its width-bin accumulator (7 f32x4 accs per lane).
// Reference semantics:
//   h0=(int)(H*r0); h1=(int)(H*r2); step=(h1-h0)/7
//   bin i<6: [h0+i*step, h0+(i+1)*step); bin 6: [h0+6*step, h1)
//   step==0 -> all valid pixels land in bin 6; empty bin -> -FLT_MAX
constexpr int H = 64, W = 64, C = 256, PH = 7, PW = 7;

typedef float f32x4 __attribute__((ext_vector_type(4)));

__global__ __launch_bounds__(64) void roi_pool_row_kernel(
    const float* __restrict__ fm, const float* __restrict__ rois,
    float* __restrict__ out, int B, int R)
{
    int bid = blockIdx.x;
    int i = bid % PH; bid /= PH;
    int r = bid % R;
    int b = bid / R;

    const float* roi = rois + ((size_t)b * R + r) * 4;
    int h0 = (int)((float)H * roi[0]);   // truncation == astype(int32), inputs >= 0
    int w0 = (int)((float)W * roi[1]);
    int h1 = (int)((float)H * roi[2]);
    int w1 = (int)((float)W * roi[3]);
    int hs = (h1 - h0) / PH;
    int ws = (w1 - w0) / PW;

    int ys, ye;
    if (hs > 0) { ys = h0 + i * hs; ye = (i < PH - 1) ? (ys + hs) : h1; }
    else        { ys = h0;          ye = (i == PH - 1) ? h1 : h0; }   // i<6 empty
    ys = max(ys, 0); ye = min(ye, H);

    const int t = threadIdx.x;           // lane 0..63 -> channels 4t..4t+3
    const float* fmb = fm + (size_t)b * H * W * C + (size_t)t * 4;

    f32x4 acc[PW];
    #pragma unroll
    for (int j = 0; j < PW; ++j)
        acc[j] = (f32x4){-FLT_MAX, -FLT_MAX, -FLT_MAX, -FLT_MAX};

    if (ws > 0) {
        const int xe_last = min(w1, W);
        for (int y = ys; y < ye; ++y) {
            const float* row = fmb + (size_t)y * W * C;
            #pragma unroll
            for (int j = 0; j < PW; ++j) {
                const int xs = w0 + j * ws;
                const int xe = (j < PW - 1) ? (xs + ws) : xe_last;
                for (int x = xs; x < xe; ++x) {
                    const f32x4 v = *reinterpret_cast<const f32x4*>(row + (size_t)x * C);
                    acc[j].x = fmaxf(acc[j].x, v.x);
                    acc[j].y = fmaxf(acc[j].y, v.y);
                    acc[j].z = fmaxf(acc[j].z, v.z);
                    acc[j].w = fmaxf(acc[j].w, v.w);
                }
            }
        }
    } else {                              // ws==0: all valid pixels -> bin 6
        const int xe = min(w1, W);
        for (int y = ys; y < ye; ++y) {
            const float* row = fmb + (size_t)y * W * C;
            for (int x = w0; x < xe; ++x) {
                const f32x4 v = *reinterpret_cast<const f32x4*>(row + (size_t)x * C);
                acc[PW - 1].x = fmaxf(acc[PW - 1].x, v.x);
                acc[PW - 1].y = fmaxf(acc[PW - 1].y, v.y);
                acc[PW - 1].z = fmaxf(acc[PW - 1].z, v.z);
                acc[PW - 1].w = fmaxf(acc[PW - 1].w, v.w);
            }
        }
    }

    size_t o = ((((size_t)b * R + r) * PH + i) * PW) * C + (size_t)t * 4;
    #pragma unroll
    for (int j = 0; j < PW; ++j)
        __builtin_nontemporal_store(acc[j],
            reinterpret_cast<f32x4*>(out + o + (size_t)j * C));
}

extern "C" void kernel_launch(void* const* d_in, const int* in_sizes, int n_in,
                              void* d_out, int out_size, void* d_ws, size_t ws_size,
                              hipStream_t stream) {
    const float* fm   = (const float*)d_in[0];
    const float* rois = (const float*)d_in[1];
    float* out = (float*)d_out;

    const int B = in_sizes[0] / (H * W * C);        // = 2
    const int R = in_sizes[1] / (B * 4);            // = 256

    const int nblocks = B * R * PH;                 // 3584 one-wave blocks
    roi_pool_row_kernel<<<nblocks, 64, 0, stream>>>(fm, rois, out, B, R);
}

// Round 4
// 42.703 us; speedup vs baseline: 4.0875x; 4.0875x over previous
//
#include <hip/hip_runtime.h>
#include <float.h>

// ROI max-pooling. One WAVE per output bin (b, r, i, j); 4 waves per block.
// b = blockIdx&1 so each XCD's L2 (4 MiB) caches exactly one image (4 MiB).
// x-loop unrolled by 4 with independent accumulators for memory-level parallelism.
// Reference semantics:
//   h0=(int)(H*r0); h1=(int)(H*r2); step=(h1-h0)/7
//   bin i<6: [h0+i*step, h0+(i+1)*step); bin 6: [h0+6*step, h1)
//   step==0 -> all valid pixels land in bin 6; empty bin -> -FLT_MAX
constexpr int H = 64, W = 64, C = 256, PH = 7, PW = 7;

typedef float f32x4 __attribute__((ext_vector_type(4)));

__device__ __forceinline__ f32x4 vmax4(f32x4 a, f32x4 b) {
    f32x4 r;
    r.x = fmaxf(a.x, b.x); r.y = fmaxf(a.y, b.y);
    r.z = fmaxf(a.z, b.z); r.w = fmaxf(a.w, b.w);
    return r;
}

__global__ __launch_bounds__(256) void roi_pool_kernel(
    const float* __restrict__ fm, const float* __restrict__ rois,
    float* __restrict__ out, int R)
{
    const int wave = threadIdx.x >> 6;            // 0..3
    const int lane = threadIdx.x & 63;            // channels 4*lane..4*lane+3

    const int b = blockIdx.x & 1;                 // batch -> XCD parity
    int m = (blockIdx.x >> 1) * 4 + wave;         // bin index within batch
    int j = m % PW; m /= PW;
    int i = m % PH; m /= PH;
    int r = m;                                    // 0..R-1

    const float* roi = rois + ((size_t)b * R + r) * 4;
    int h0 = (int)((float)H * roi[0]);            // trunc == astype(int32), >=0
    int w0 = (int)((float)W * roi[1]);
    int h1 = (int)((float)H * roi[2]);
    int w1 = (int)((float)W * roi[3]);
    int hs = (h1 - h0) / PH;
    int ws = (w1 - w0) / PW;

    int ys, ye, xs, xe;
    if (hs > 0) { ys = h0 + i * hs; ye = (i < PH - 1) ? (ys + hs) : h1; }
    else        { ys = h0;          ye = (i == PH - 1) ? h1 : h0; }   // i<6 empty
    if (ws > 0) { xs = w0 + j * ws; xe = (j < PW - 1) ? (xs + ws) : w1; }
    else        { xs = w0;          xe = (j == PW - 1) ? w1 : w0; }
    ys = max(ys, 0); ye = min(ye, H);
    xs = max(xs, 0); xe = min(xe, W);

    const f32x4 NEG = (f32x4){-FLT_MAX, -FLT_MAX, -FLT_MAX, -FLT_MAX};
    f32x4 a0 = NEG, a1 = NEG, a2 = NEG, a3 = NEG;

    const float* fmb = fm + (size_t)b * H * W * C + (size_t)lane * 4;
    for (int y = ys; y < ye; ++y) {
        const float* row = fmb + (size_t)y * W * C;
        int x = xs;
        for (; x + 4 <= xe; x += 4) {             // 4 independent loads in flight
            f32x4 v0 = *reinterpret_cast<const f32x4*>(row + (size_t)(x + 0) * C);
            f32x4 v1 = *reinterpret_cast<const f32x4*>(row + (size_t)(x + 1) * C);
            f32x4 v2 = *reinterpret_cast<const f32x4*>(row + (size_t)(x + 2) * C);
            f32x4 v3 = *reinterpret_cast<const f32x4*>(row + (size_t)(x + 3) * C);
            a0 = vmax4(a0, v0); a1 = vmax4(a1, v1);
            a2 = vmax4(a2, v2); a3 = vmax4(a3, v3);
        }
        if (x + 2 <= xe) {
            f32x4 v0 = *reinterpret_cast<const f32x4*>(row + (size_t)(x + 0) * C);
            f32x4 v1 = *reinterpret_cast<const f32x4*>(row + (size_t)(x + 1) * C);
            a0 = vmax4(a0, v0); a1 = vmax4(a1, v1);
            x += 2;
        }
        if (x < xe) {
            f32x4 v0 = *reinterpret_cast<const f32x4*>(row + (size_t)x * C);
            a2 = vmax4(a2, v0);
        }
    }
    f32x4 acc = vmax4(vmax4(a0, a1), vmax4(a2, a3));

    size_t o = ((((size_t)b * R + r) * PH + i) * PW + j) * C + (size_t)lane * 4;
    __builtin_nontemporal_store(acc, reinterpret_cast<f32x4*>(out + o));
}

extern "C" void kernel_launch(void* const* d_in, const int* in_sizes, int n_in,
                              void* d_out, int out_size, void* d_ws, size_t ws_size,
                              hipStream_t stream) {
    const float* fm   = (const float*)d_in[0];
    const float* rois = (const float*)d_in[1];
    float* out = (float*)d_out;

    const int B = in_sizes[0] / (H * W * C);        // = 2
    const int R = in_sizes[1] / (B * 4);            // = 256

    // bins per batch = R*PH*PW = 12544, 4 per block -> 3136 blocks per batch
    const int nblocks = B * (R * PH * PW / 4);      // 6272 blocks x 256 threads
    roi_pool_kernel<<<nblocks, 256, 0, stream>>>(fm, rois, out, R);
}

// Round 5
// 42.511 us; speedup vs baseline: 4.1060x; 1.0045x over previous
//
#include <hip/hip_runtime.h>
#include <float.h>

// ROI max-pooling. One WAVE per output bin (b, r, i, j); 4 waves per block.
// b = blockIdx&1 so each XCD's L2 (4 MiB) caches exactly one image (4 MiB).
// All loop bounds forced wave-uniform via readfirstlane so addressing lives
// on the SALU (global_load saddr form); tail branches eliminated by the
// max-idempotent clamp trick (duplicate pixels are harmless under fmax).
// Reference semantics:
//   h0=(int)(H*r0); h1=(int)(H*r2); step=(h1-h0)/7
//   bin i<6: [h0+i*step, h0+(i+1)*step); bin 6: [h0+6*step, h1)
//   step==0 -> all valid pixels land in bin 6; empty bin -> -FLT_MAX
constexpr int H = 64, W = 64, C = 256, PH = 7, PW = 7;

typedef float f32x4 __attribute__((ext_vector_type(4)));

__device__ __forceinline__ f32x4 vmax4(f32x4 a, f32x4 b) {
    f32x4 r;
    r.x = fmaxf(a.x, b.x); r.y = fmaxf(a.y, b.y);
    r.z = fmaxf(a.z, b.z); r.w = fmaxf(a.w, b.w);
    return r;
}

__global__ __launch_bounds__(256) void roi_pool_kernel(
    const float* __restrict__ fm, const float* __restrict__ rois,
    float* __restrict__ out, int R)
{
    const int lane = threadIdx.x & 63;                       // channels 4*lane..
    const int wave = __builtin_amdgcn_readfirstlane(threadIdx.x >> 6); // 0..3, uniform

    const int b = blockIdx.x & 1;                            // batch -> XCD parity
    int m = (blockIdx.x >> 1) * 4 + wave;                    // bin index in batch
    int j = m % PW; m /= PW;
    int i = m % PH; m /= PH;
    int r = m;                                               // 0..R-1

    const float* roi = rois + ((size_t)b * R + r) * 4;
    int h0 = (int)((float)H * roi[0]);                       // trunc == astype(int32)
    int w0 = (int)((float)W * roi[1]);
    int h1 = (int)((float)H * roi[2]);
    int w1 = (int)((float)W * roi[3]);
    int hs = (h1 - h0) / PH;
    int ws = (w1 - w0) / PW;

    int ys, ye, xs, xe;
    if (hs > 0) { ys = h0 + i * hs; ye = (i < PH - 1) ? (ys + hs) : h1; }
    else        { ys = h0;          ye = (i == PH - 1) ? h1 : h0; }   // i<6 empty
    if (ws > 0) { xs = w0 + j * ws; xe = (j < PW - 1) ? (xs + ws) : w1; }
    else        { xs = w0;          xe = (j == PW - 1) ? w1 : w0; }
    ys = __builtin_amdgcn_readfirstlane(max(ys, 0));
    ye = __builtin_amdgcn_readfirstlane(min(ye, H));
    xs = __builtin_amdgcn_readfirstlane(max(xs, 0));
    xe = __builtin_amdgcn_readfirstlane(min(xe, W));

    const f32x4 NEG = {-FLT_MAX, -FLT_MAX, -FLT_MAX, -FLT_MAX};
    f32x4 a0 = NEG, a1 = NEG, a2 = NEG, a3 = NEG;

    const float* fmb = fm + (size_t)b * (H * W * C);         // uniform base
    const int lo = lane * 4;                                 // only divergent term

    for (int y = ys; y < ye; y += 2) {
        const int y1 = min(y + 1, ye - 1);                   // clamp: dup row ok
        const int ro0 = y  * (W * C);                        // uniform offsets
        const int ro1 = y1 * (W * C);
        for (int x = xs; x < xe; x += 2) {
            const int x1 = min(x + 1, xe - 1);               // clamp: dup col ok
            const f32x4 v0 = *(const f32x4*)(fmb + ro0 + x  * C + lo);
            const f32x4 v1 = *(const f32x4*)(fmb + ro0 + x1 * C + lo);
            const f32x4 v2 = *(const f32x4*)(fmb + ro1 + x  * C + lo);
            const f32x4 v3 = *(const f32x4*)(fmb + ro1 + x1 * C + lo);
            a0 = vmax4(a0, v0); a1 = vmax4(a1, v1);
            a2 = vmax4(a2, v2); a3 = vmax4(a3, v3);
        }
    }
    f32x4 acc = vmax4(vmax4(a0, a1), vmax4(a2, a3));

    size_t o = ((((size_t)b * R + r) * PH + i) * PW + j) * C + (size_t)lo;
    __builtin_nontemporal_store(acc, reinterpret_cast<f32x4*>(out + o));
}

extern "C" void kernel_launch(void* const* d_in, const int* in_sizes, int n_in,
                              void* d_out, int out_size, void* d_ws, size_t ws_size,
                              hipStream_t stream) {
    const float* fm   = (const float*)d_in[0];
    const float* rois = (const float*)d_in[1];
    float* out = (float*)d_out;

    const int B = in_sizes[0] / (H * W * C);        // = 2
    const int R = in_sizes[1] / (B * 4);            // = 256

    const int nblocks = B * (R * PH * PW / 4);      // 6272 blocks x 256 threads
    roi_pool_kernel<<<nblocks, 256, 0, stream>>>(fm, rois, out, R);
}

// Round 6
// 31.120 us; speedup vs baseline: 5.6090x; 1.3661x over previous
//
#include <hip/hip_runtime.h>
#include <float.h>

// ROI max-pool via sliding-4-max pyramid.
//   S4x[y][x]  = max fm[y][x..x+3]   (x clamped at W-1)
//   S4y[y][x]  = max fm[y..y+3][x]
//   S4xy[y][x] = max fm[y..y+3][x..x+3]
// Any bin range of length L>=4 is covered by ceil(L/4) overlapping spans
// (last span at e-4; overlap is free under fmax). L in {2,3} -> singles.
// Tables live in d_ws (24 MB); if ws is too small, fall back to the
// verified direct kernel.
// Reference semantics:
//   h0=(int)(H*r0); h1=(int)(H*r2); step=(h1-h0)/7
//   bin i<6: [h0+i*step, h0+(i+1)*step); bin 6: [h0+6*step, h1)
//   step==0 -> all valid pixels in bin 6; empty bin -> -FLT_MAX
constexpr int H = 64, W = 64, C = 256, PH = 7, PW = 7;

typedef float f32x4 __attribute__((ext_vector_type(4)));

__device__ __forceinline__ f32x4 vmax4(f32x4 a, f32x4 b) {
    f32x4 r;
    r.x = fmaxf(a.x, b.x); r.y = fmaxf(a.y, b.y);
    r.z = fmaxf(a.z, b.z); r.w = fmaxf(a.w, b.w);
    return r;
}

// ---- build kernels: one wave per (b, y, x); lane owns 4 channels ----
__global__ __launch_bounds__(256) void build_s4x(
    const float* __restrict__ fm, float* __restrict__ s4x)
{
    const int wave = threadIdx.x >> 6, lane = threadIdx.x & 63;
    const int b = blockIdx.x & 1;                       // XCD parity
    const int pix = (blockIdx.x >> 1) * 4 + wave;       // [0, H*W)
    const int y = pix >> 6, x = pix & 63;

    const float* rb = fm + ((size_t)(b * H + y) * W) * C + lane * 4;
    const int x1 = min(x + 1, W - 1), x2 = min(x + 2, W - 1), x3 = min(x + 3, W - 1);
    f32x4 v0 = *(const f32x4*)(rb + x  * C);
    f32x4 v1 = *(const f32x4*)(rb + x1 * C);
    f32x4 v2 = *(const f32x4*)(rb + x2 * C);
    f32x4 v3 = *(const f32x4*)(rb + x3 * C);
    f32x4 mx = vmax4(vmax4(v0, v1), vmax4(v2, v3));
    *(f32x4*)(s4x + ((size_t)(b * H + y) * W + x) * C + lane * 4) = mx;
}

__global__ __launch_bounds__(256) void build_s4y_s4xy(
    const float* __restrict__ fm, const float* __restrict__ s4x,
    float* __restrict__ s4y, float* __restrict__ s4xy)
{
    const int wave = threadIdx.x >> 6, lane = threadIdx.x & 63;
    const int b = blockIdx.x & 1;
    const int pix = (blockIdx.x >> 1) * 4 + wave;
    const int y = pix >> 6, x = pix & 63;

    const int y1 = min(y + 1, H - 1), y2 = min(y + 2, H - 1), y3 = min(y + 3, H - 1);
    const size_t colbase = (size_t)b * H * W * C + (size_t)x * C + lane * 4;
    const size_t rs = (size_t)W * C;

    f32x4 a0 = *(const f32x4*)(fm + colbase + (size_t)y  * rs);
    f32x4 a1 = *(const f32x4*)(fm + colbase + (size_t)y1 * rs);
    f32x4 a2 = *(const f32x4*)(fm + colbase + (size_t)y2 * rs);
    f32x4 a3 = *(const f32x4*)(fm + colbase + (size_t)y3 * rs);
    f32x4 c0 = *(const f32x4*)(s4x + colbase + (size_t)y  * rs);
    f32x4 c1 = *(const f32x4*)(s4x + colbase + (size_t)y1 * rs);
    f32x4 c2 = *(const f32x4*)(s4x + colbase + (size_t)y2 * rs);
    f32x4 c3 = *(const f32x4*)(s4x + colbase + (size_t)y3 * rs);

    const size_t o = ((size_t)(b * H + y) * W + x) * C + lane * 4;
    *(f32x4*)(s4y  + o) = vmax4(vmax4(a0, a1), vmax4(a2, a3));
    *(f32x4*)(s4xy + o) = vmax4(vmax4(c0, c1), vmax4(c2, c3));
}

// ---- query: one wave per bin (b, r, i, j); 4 waves per block ----
__global__ __launch_bounds__(256) void roi_pool_q(
    const float* __restrict__ fm, const float* __restrict__ rois,
    const float* __restrict__ s4x, const float* __restrict__ s4y,
    const float* __restrict__ s4xy, float* __restrict__ out, int R)
{
    const int lane = threadIdx.x & 63;
    const int wave = __builtin_amdgcn_readfirstlane(threadIdx.x >> 6);

    const int b = blockIdx.x & 1;                       // batch -> XCD parity
    int m = (blockIdx.x >> 1) * 4 + wave;
    int j = m % PW; m /= PW;
    int i = m % PH; m /= PH;
    int r = m;

    const float* roi = rois + ((size_t)b * R + r) * 4;
    int h0 = (int)((float)H * roi[0]);                  // trunc == astype(int32)
    int w0 = (int)((float)W * roi[1]);
    int h1 = (int)((float)H * roi[2]);
    int w1 = (int)((float)W * roi[3]);
    int hs = (h1 - h0) / PH;
    int ws = (w1 - w0) / PW;

    int ys, ye, xs, xe;
    if (hs > 0) { ys = h0 + i * hs; ye = (i < PH - 1) ? (ys + hs) : h1; }
    else        { ys = h0;          ye = (i == PH - 1) ? h1 : h0; }
    if (ws > 0) { xs = w0 + j * ws; xe = (j < PW - 1) ? (xs + ws) : w1; }
    else        { xs = w0;          xe = (j == PW - 1) ? w1 : w0; }
    ys = __builtin_amdgcn_readfirstlane(max(ys, 0));
    ye = __builtin_amdgcn_readfirstlane(min(ye, H));
    xs = __builtin_amdgcn_readfirstlane(max(xs, 0));
    xe = __builtin_amdgcn_readfirstlane(min(xe, W));

    const int hl = ye - ys, wl = xe - xs;
    f32x4 acc = {-FLT_MAX, -FLT_MAX, -FLT_MAX, -FLT_MAX};

    if (hl > 0 && wl > 0) {
        const bool y4 = hl >= 4, x4 = wl >= 4;
        const int ny = y4 ? (hl + 3) >> 2 : hl;
        const int nx = x4 ? (wl + 3) >> 2 : wl;
        const int ystep = y4 ? 4 : 1, xstep = x4 ? 4 : 1;
        const int ycl = y4 ? ye - 4 : ye - 1;
        const int xcl = x4 ? xe - 4 : xe - 1;
        const float* tb = y4 ? (x4 ? s4xy : s4y) : (x4 ? s4x : fm);
        const float* tbb = tb + (size_t)b * H * W * C + lane * 4;

        for (int ky = 0; ky < ny; ++ky) {
            const int y = min(ys + ystep * ky, ycl);
            const float* rowp = tbb + (size_t)y * W * C;
            for (int kx = 0; kx < nx; ++kx) {
                const int x = min(xs + xstep * kx, xcl);
                acc = vmax4(acc, *(const f32x4*)(rowp + (size_t)x * C));
            }
        }
    }

    size_t o = ((((size_t)b * R + r) * PH + i) * PW + j) * C + (size_t)lane * 4;
    __builtin_nontemporal_store(acc, reinterpret_cast<f32x4*>(out + o));
}

// ---- verified fallback (R5 kernel) if ws too small ----
__global__ __launch_bounds__(256) void roi_pool_direct(
    const float* __restrict__ fm, const float* __restrict__ rois,
    float* __restrict__ out, int R)
{
    const int lane = threadIdx.x & 63;
    const int wave = __builtin_amdgcn_readfirstlane(threadIdx.x >> 6);
    const int b = blockIdx.x & 1;
    int m = (blockIdx.x >> 1) * 4 + wave;
    int j = m % PW; m /= PW;
    int i = m % PH; m /= PH;
    int r = m;

    const float* roi = rois + ((size_t)b * R + r) * 4;
    int h0 = (int)((float)H * roi[0]);
    int w0 = (int)((float)W * roi[1]);
    int h1 = (int)((float)H * roi[2]);
    int w1 = (int)((float)W * roi[3]);
    int hs = (h1 - h0) / PH;
    int ws = (w1 - w0) / PW;

    int ys, ye, xs, xe;
    if (hs > 0) { ys = h0 + i * hs; ye = (i < PH - 1) ? (ys + hs) : h1; }
    else        { ys = h0;          ye = (i == PH - 1) ? h1 : h0; }
    if (ws > 0) { xs = w0 + j * ws; xe = (j < PW - 1) ? (xs + ws) : w1; }
    else        { xs = w0;          xe = (j == PW - 1) ? w1 : w0; }
    ys = __builtin_amdgcn_readfirstlane(max(ys, 0));
    ye = __builtin_amdgcn_readfirstlane(min(ye, H));
    xs = __builtin_amdgcn_readfirstlane(max(xs, 0));
    xe = __builtin_amdgcn_readfirstlane(min(xe, W));

    const f32x4 NEG = {-FLT_MAX, -FLT_MAX, -FLT_MAX, -FLT_MAX};
    f32x4 a0 = NEG, a1 = NEG, a2 = NEG, a3 = NEG;
    const float* fmb = fm + (size_t)b * (H * W * C);
    const int lo = lane * 4;

    for (int y = ys; y < ye; y += 2) {
        const int y1 = min(y + 1, ye - 1);
        const int ro0 = y  * (W * C);
        const int ro1 = y1 * (W * C);
        for (int x = xs; x < xe; x += 2) {
            const int x1 = min(x + 1, xe - 1);
            a0 = vmax4(a0, *(const f32x4*)(fmb + ro0 + x  * C + lo));
            a1 = vmax4(a1, *(const f32x4*)(fmb + ro0 + x1 * C + lo));
            a2 = vmax4(a2, *(const f32x4*)(fmb + ro1 + x  * C + lo));
            a3 = vmax4(a3, *(const f32x4*)(fmb + ro1 + x1 * C + lo));
        }
    }
    f32x4 acc = vmax4(vmax4(a0, a1), vmax4(a2, a3));
    size_t o = ((((size_t)b * R + r) * PH + i) * PW + j) * C + (size_t)lo;
    __builtin_nontemporal_store(acc, reinterpret_cast<f32x4*>(out + o));
}

extern "C" void kernel_launch(void* const* d_in, const int* in_sizes, int n_in,
                              void* d_out, int out_size, void* d_ws, size_t ws_size,
                              hipStream_t stream) {
    const float* fm   = (const float*)d_in[0];
    const float* rois = (const float*)d_in[1];
    float* out = (float*)d_out;

    const int B = in_sizes[0] / (H * W * C);        // = 2
    const int R = in_sizes[1] / (B * 4);            // = 256

    const size_t tbl = (size_t)B * H * W * C;       // floats per table
    const size_t need = 3 * tbl * sizeof(float);    // 24 MB for B=2
    const int qblocks = B * (R * PH * PW / 4);      // 6272

    if (B == 2 && ws_size >= need) {
        float* s4x  = (float*)d_ws;
        float* s4y  = s4x + tbl;
        float* s4xy = s4y + tbl;
        const int bblocks = B * H * W / 4;          // 2048
        build_s4x    <<<bblocks, 256, 0, stream>>>(fm, s4x);
        build_s4y_s4xy<<<bblocks, 256, 0, stream>>>(fm, s4x, s4y, s4xy);
        roi_pool_q   <<<qblocks, 256, 0, stream>>>(fm, rois, s4x, s4y, s4xy, out, R);
    } else {
        roi_pool_direct<<<qblocks, 256, 0, stream>>>(fm, rois, out, R);
    }
}

// Round 7
// 27.930 us; speedup vs baseline: 6.2495x; 1.1142x over previous
//
#include <hip/hip_runtime.h>
#include <float.h>

// ROI max-pool via sliding-4-max pyramid, 2-kernel version.
//   S4x[y][x]  = max fm[y][x..x+3]   (indices clamped at edge)
//   S4y[y][x]  = max fm[y..y+3][x]
//   S4xy[y][x] = max fm[y..y+3][x..x+3]
// Build fused into ONE kernel: block = 4 waves = rows y0..y0+3 at column x.
// Waves cooperatively load the 7-row halo, compute s4x in-reg, stage
// {fm, s4x} in LDS, then combine 4 rows for s4y/s4xy.
// Query: any bin range of length L>=4 covered by ceil(L/4) overlapping
// 4-spans (last at e-4; overlap free under fmax); L in {2,3} -> singles.
// Reference semantics:
//   h0=(int)(H*r0); h1=(int)(H*r2); step=(h1-h0)/7
//   bin i<6: [h0+i*step, h0+(i+1)*step); bin 6: [h0+6*step, h1)
//   step==0 -> all valid pixels in bin 6; empty bin -> -FLT_MAX
constexpr int H = 64, W = 64, C = 256, PH = 7, PW = 7;

typedef float f32x4 __attribute__((ext_vector_type(4)));

__device__ __forceinline__ f32x4 vmax4(f32x4 a, f32x4 b) {
    f32x4 r;
    r.x = fmaxf(a.x, b.x); r.y = fmaxf(a.y, b.y);
    r.z = fmaxf(a.z, b.z); r.w = fmaxf(a.w, b.w);
    return r;
}

// ---- fused build: grid = B * W * (H/4) blocks of 256 ----
__global__ __launch_bounds__(256) void build_tables(
    const float* __restrict__ fm, float* __restrict__ s4x,
    float* __restrict__ s4y, float* __restrict__ s4xy)
{
    __shared__ f32x4 lds_fm[7][64];    // fm[y0+k][x] channel quads
    __shared__ f32x4 lds_sx[7][64];    // s4x[y0+k][x]

    const int lane = threadIdx.x & 63;
    const int wave = __builtin_amdgcn_readfirstlane(threadIdx.x >> 6); // 0..3

    const int b = blockIdx.x & 1;                    // batch -> XCD parity
    const int p = blockIdx.x >> 1;                   // [0, W*H/4)
    const int x = p & (W - 1);
    const int y0 = (p >> 6) << 2;

    const int x1 = min(x + 1, W - 1), x2 = min(x + 2, W - 1), x3 = min(x + 3, W - 1);
    const float* fmb = fm + (size_t)b * H * W * C + (size_t)lane * 4;

    // wave w owns halo slots {w} and (w<3 ? {4+w} : {})
    #pragma unroll
    for (int s = 0; s < 2; ++s) {
        const int slot = wave + 4 * s;
        if (slot < 7) {
            const int y = min(y0 + slot, H - 1);     // clamp == table edge rule
            const float* row = fmb + (size_t)y * W * C;
            f32x4 v0 = *(const f32x4*)(row + (size_t)x  * C);
            f32x4 v1 = *(const f32x4*)(row + (size_t)x1 * C);
            f32x4 v2 = *(const f32x4*)(row + (size_t)x2 * C);
            f32x4 v3 = *(const f32x4*)(row + (size_t)x3 * C);
            lds_fm[slot][lane] = v0;
            lds_sx[slot][lane] = vmax4(vmax4(v0, v1), vmax4(v2, v3));
        }
    }
    __syncthreads();

    const int y = y0 + wave;
    const f32x4 sx = lds_sx[wave][lane];
    const f32x4 sy = vmax4(vmax4(lds_fm[wave][lane],     lds_fm[wave + 1][lane]),
                           vmax4(lds_fm[wave + 2][lane], lds_fm[wave + 3][lane]));
    const f32x4 sxy = vmax4(vmax4(lds_sx[wave][lane],     lds_sx[wave + 1][lane]),
                            vmax4(lds_sx[wave + 2][lane], lds_sx[wave + 3][lane]));

    const size_t o = ((size_t)(b * H + y) * W + x) * C + (size_t)lane * 4;
    *(f32x4*)(s4x  + o) = sx;
    *(f32x4*)(s4y  + o) = sy;
    *(f32x4*)(s4xy + o) = sxy;
}

// ---- query: one wave per bin (b, r, i, j); 4 waves per block ----
__global__ __launch_bounds__(256) void roi_pool_q(
    const float* __restrict__ fm, const float* __restrict__ rois,
    const float* __restrict__ s4x, const float* __restrict__ s4y,
    const float* __restrict__ s4xy, float* __restrict__ out, int R)
{
    const int lane = threadIdx.x & 63;
    const int wave = __builtin_amdgcn_readfirstlane(threadIdx.x >> 6);

    const int b = blockIdx.x & 1;                       // batch -> XCD parity
    int m = (blockIdx.x >> 1) * 4 + wave;
    int j = m % PW; m /= PW;
    int i = m % PH; m /= PH;
    int r = m;

    const float* roi = rois + ((size_t)b * R + r) * 4;
    int h0 = (int)((float)H * roi[0]);                  // trunc == astype(int32)
    int w0 = (int)((float)W * roi[1]);
    int h1 = (int)((float)H * roi[2]);
    int w1 = (int)((float)W * roi[3]);
    int hs = (h1 - h0) / PH;
    int ws = (w1 - w0) / PW;

    int ys, ye, xs, xe;
    if (hs > 0) { ys = h0 + i * hs; ye = (i < PH - 1) ? (ys + hs) : h1; }
    else        { ys = h0;          ye = (i == PH - 1) ? h1 : h0; }
    if (ws > 0) { xs = w0 + j * ws; xe = (j < PW - 1) ? (xs + ws) : w1; }
    else        { xs = w0;          xe = (j == PW - 1) ? w1 : w0; }
    ys = __builtin_amdgcn_readfirstlane(max(ys, 0));
    ye = __builtin_amdgcn_readfirstlane(min(ye, H));
    xs = __builtin_amdgcn_readfirstlane(max(xs, 0));
    xe = __builtin_amdgcn_readfirstlane(min(xe, W));

    const int hl = ye - ys, wl = xe - xs;
    f32x4 acc = {-FLT_MAX, -FLT_MAX, -FLT_MAX, -FLT_MAX};

    if (hl > 0 && wl > 0) {
        const bool y4 = hl >= 4, x4 = wl >= 4;
        const int ny = y4 ? (hl + 3) >> 2 : hl;
        const int nx = x4 ? (wl + 3) >> 2 : wl;
        const int ystep = y4 ? 4 : 1, xstep = x4 ? 4 : 1;
        const int ycl = y4 ? ye - 4 : ye - 1;
        const int xcl = x4 ? xe - 4 : xe - 1;
        const float* tb = y4 ? (x4 ? s4xy : s4y) : (x4 ? s4x : fm);
        const float* tbb = tb + (size_t)b * H * W * C + lane * 4;

        for (int ky = 0; ky < ny; ++ky) {
            const int y = min(ys + ystep * ky, ycl);
            const float* rowp = tbb + (size_t)y * W * C;
            for (int kx = 0; kx < nx; ++kx) {
                const int x = min(xs + xstep * kx, xcl);
                acc = vmax4(acc, *(const f32x4*)(rowp + (size_t)x * C));
            }
        }
    }

    size_t o = ((((size_t)b * R + r) * PH + i) * PW + j) * C + (size_t)lane * 4;
    __builtin_nontemporal_store(acc, reinterpret_cast<f32x4*>(out + o));
}

// ---- verified fallback (R5 kernel) if ws too small ----
__global__ __launch_bounds__(256) void roi_pool_direct(
    const float* __restrict__ fm, const float* __restrict__ rois,
    float* __restrict__ out, int R)
{
    const int lane = threadIdx.x & 63;
    const int wave = __builtin_amdgcn_readfirstlane(threadIdx.x >> 6);
    const int b = blockIdx.x & 1;
    int m = (blockIdx.x >> 1) * 4 + wave;
    int j = m % PW; m /= PW;
    int i = m % PH; m /= PH;
    int r = m;

    const float* roi = rois + ((size_t)b * R + r) * 4;
    int h0 = (int)((float)H * roi[0]);
    int w0 = (int)((float)W * roi[1]);
    int h1 = (int)((float)H * roi[2]);
    int w1 = (int)((float)W * roi[3]);
    int hs = (h1 - h0) / PH;
    int ws = (w1 - w0) / PW;

    int ys, ye, xs, xe;
    if (hs > 0) { ys = h0 + i * hs; ye = (i < PH - 1) ? (ys + hs) : h1; }
    else        { ys = h0;          ye = (i == PH - 1) ? h1 : h0; }
    if (ws > 0) { xs = w0 + j * ws; xe = (j < PW - 1) ? (xs + ws) : w1; }
    else        { xs = w0;          xe = (j == PW - 1) ? w1 : w0; }
    ys = __builtin_amdgcn_readfirstlane(max(ys, 0));
    ye = __builtin_amdgcn_readfirstlane(min(ye, H));
    xs = __builtin_amdgcn_readfirstlane(max(xs, 0));
    xe = __builtin_amdgcn_readfirstlane(min(xe, W));

    const f32x4 NEG = {-FLT_MAX, -FLT_MAX, -FLT_MAX, -FLT_MAX};
    f32x4 a0 = NEG, a1 = NEG, a2 = NEG, a3 = NEG;
    const float* fmb = fm + (size_t)b * (H * W * C);
    const int lo = lane * 4;

    for (int y = ys; y < ye; y += 2) {
        const int y1 = min(y + 1, ye - 1);
        const int ro0 = y  * (W * C);
        const int ro1 = y1 * (W * C);
        for (int x = xs; x < xe; x += 2) {
            const int x1 = min(x + 1, xe - 1);
            a0 = vmax4(a0, *(const f32x4*)(fmb + ro0 + x  * C + lo));
            a1 = vmax4(a1, *(const f32x4*)(fmb + ro0 + x1 * C + lo));
            a2 = vmax4(a2, *(const f32x4*)(fmb + ro1 + x  * C + lo));
            a3 = vmax4(a3, *(const f32x4*)(fmb + ro1 + x1 * C + lo));
        }
    }
    f32x4 acc = vmax4(vmax4(a0, a1), vmax4(a2, a3));
    size_t o = ((((size_t)b * R + r) * PH + i) * PW + j) * C + (size_t)lo;
    __builtin_nontemporal_store(acc, reinterpret_cast<f32x4*>(out + o));
}

extern "C" void kernel_launch(void* const* d_in, const int* in_sizes, int n_in,
                              void* d_out, int out_size, void* d_ws, size_t ws_size,
                              hipStream_t stream) {
    const float* fm   = (const float*)d_in[0];
    const float* rois = (const float*)d_in[1];
    float* out = (float*)d_out;

    const int B = in_sizes[0] / (H * W * C);        // = 2
    const int R = in_sizes[1] / (B * 4);            // = 256

    const size_t tbl = (size_t)B * H * W * C;       // floats per table
    const size_t need = 3 * tbl * sizeof(float);    // 24 MB for B=2
    const int qblocks = B * (R * PH * PW / 4);      // 6272

    if (B == 2 && ws_size >= need) {
        float* s4x  = (float*)d_ws;
        float* s4y  = s4x + tbl;
        float* s4xy = s4y + tbl;
        const int bblocks = B * W * (H / 4);        // 2048
        build_tables<<<bblocks, 256, 0, stream>>>(fm, s4x, s4y, s4xy);
        roi_pool_q  <<<qblocks, 256, 0, stream>>>(fm, rois, s4x, s4y, s4xy, out, R);
    } else {
        roi_pool_direct<<<qblocks, 256, 0, stream>>>(fm, rois, out, R);
    }
}

// Round 8
// 27.217 us; speedup vs baseline: 6.4133x; 1.0262x over previous
//
#include <hip/hip_runtime.h>
#include <float.h>

// ROI max-pool via sliding-4-max pyramid, 2-kernel version.
//   S4x[y][x]  = max fm[y][x..x+3]   (indices clamped at edge)
//   S4y[y][x]  = max fm[y..y+3][x]
//   S4xy[y][x] = max fm[y..y+3][x..x+3]
// Build fused into ONE kernel (LDS halo). Query: bin ranges (length<=15)
// covered by <=4 spans per dim -> fully-unrolled 4x4 span grid with
// wave-uniform guards (no loop-carried chains, up to 16 loads in flight).
// Reference semantics:
//   h0=(int)(H*r0); h1=(int)(H*r2); step=(h1-h0)/7
//   bin i<6: [h0+i*step, h0+(i+1)*step); bin 6: [h0+6*step, h1)
//   step==0 -> all valid pixels in bin 6; empty bin -> -FLT_MAX
constexpr int H = 64, W = 64, C = 256, PH = 7, PW = 7;

typedef float f32x4 __attribute__((ext_vector_type(4)));

__device__ __forceinline__ f32x4 vmax4(f32x4 a, f32x4 b) {
    f32x4 r;
    r.x = fmaxf(a.x, b.x); r.y = fmaxf(a.y, b.y);
    r.z = fmaxf(a.z, b.z); r.w = fmaxf(a.w, b.w);
    return r;
}

// ---- fused build: grid = B * W * (H/4) blocks of 256 ----
__global__ __launch_bounds__(256) void build_tables(
    const float* __restrict__ fm, float* __restrict__ s4x,
    float* __restrict__ s4y, float* __restrict__ s4xy)
{
    __shared__ f32x4 lds_fm[7][64];    // fm[y0+k][x] channel quads
    __shared__ f32x4 lds_sx[7][64];    // s4x[y0+k][x]

    const int lane = threadIdx.x & 63;
    const int wave = __builtin_amdgcn_readfirstlane(threadIdx.x >> 6); // 0..3

    const int b = blockIdx.x & 1;                    // batch -> XCD parity
    const int p = blockIdx.x >> 1;                   // [0, W*H/4)
    const int x = p & (W - 1);
    const int y0 = (p >> 6) << 2;

    const int x1 = min(x + 1, W - 1), x2 = min(x + 2, W - 1), x3 = min(x + 3, W - 1);
    const float* fmb = fm + (size_t)b * H * W * C + (size_t)lane * 4;

    // wave w owns halo slots {w} and (w<3 ? {4+w} : {})
    #pragma unroll
    for (int s = 0; s < 2; ++s) {
        const int slot = wave + 4 * s;
        if (slot < 7) {
            const int y = min(y0 + slot, H - 1);     // clamp == table edge rule
            const float* row = fmb + (size_t)y * W * C;
            f32x4 v0 = *(const f32x4*)(row + (size_t)x  * C);
            f32x4 v1 = *(const f32x4*)(row + (size_t)x1 * C);
            f32x4 v2 = *(const f32x4*)(row + (size_t)x2 * C);
            f32x4 v3 = *(const f32x4*)(row + (size_t)x3 * C);
            lds_fm[slot][lane] = v0;
            lds_sx[slot][lane] = vmax4(vmax4(v0, v1), vmax4(v2, v3));
        }
    }
    __syncthreads();

    const int y = y0 + wave;
    const f32x4 sx = lds_sx[wave][lane];
    const f32x4 sy = vmax4(vmax4(lds_fm[wave][lane],     lds_fm[wave + 1][lane]),
                           vmax4(lds_fm[wave + 2][lane], lds_fm[wave + 3][lane]));
    const f32x4 sxy = vmax4(vmax4(lds_sx[wave][lane],     lds_sx[wave + 1][lane]),
                            vmax4(lds_sx[wave + 2][lane], lds_sx[wave + 3][lane]));

    const size_t o = ((size_t)(b * H + y) * W + x) * C + (size_t)lane * 4;
    *(f32x4*)(s4x  + o) = sx;
    *(f32x4*)(s4y  + o) = sy;
    *(f32x4*)(s4xy + o) = sxy;
}

// ---- query: one wave per bin (b, r, i, j); 4 waves per block ----
__global__ __launch_bounds__(256) void roi_pool_q(
    const float* __restrict__ fm, const float* __restrict__ rois,
    const float* __restrict__ s4x, const float* __restrict__ s4y,
    const float* __restrict__ s4xy, float* __restrict__ out, int R)
{
    const int lane = threadIdx.x & 63;
    const int wave = __builtin_amdgcn_readfirstlane(threadIdx.x >> 6);

    const int b = blockIdx.x & 1;                       // batch -> XCD parity
    int m = (blockIdx.x >> 1) * 4 + wave;
    int j = m % PW; m /= PW;
    int i = m % PH; m /= PH;
    int r = m;

    const float* roi = rois + ((size_t)b * R + r) * 4;
    int h0 = (int)((float)H * roi[0]);                  // trunc == astype(int32)
    int w0 = (int)((float)W * roi[1]);
    int h1 = (int)((float)H * roi[2]);
    int w1 = (int)((float)W * roi[3]);
    int hs = (h1 - h0) / PH;
    int ws = (w1 - w0) / PW;

    int ys, ye, xs, xe;
    if (hs > 0) { ys = h0 + i * hs; ye = (i < PH - 1) ? (ys + hs) : h1; }
    else        { ys = h0;          ye = (i == PH - 1) ? h1 : h0; }
    if (ws > 0) { xs = w0 + j * ws; xe = (j < PW - 1) ? (xs + ws) : w1; }
    else        { xs = w0;          xe = (j == PW - 1) ? w1 : w0; }
    ys = __builtin_amdgcn_readfirstlane(max(ys, 0));
    ye = __builtin_amdgcn_readfirstlane(min(ye, H));
    xs = __builtin_amdgcn_readfirstlane(max(xs, 0));
    xe = __builtin_amdgcn_readfirstlane(min(xe, W));

    const int hl = ye - ys, wl = xe - xs;
    const f32x4 NEG = {-FLT_MAX, -FLT_MAX, -FLT_MAX, -FLT_MAX};
    f32x4 a0 = NEG, a1 = NEG, a2 = NEG, a3 = NEG;   // per-kx-slot accumulators

    if (hl > 0 && wl > 0) {
        // bin length <= 15 always -> <=4 spans per dim
        const bool y4 = hl >= 4, x4 = wl >= 4;
        const int ny = y4 ? (hl + 3) >> 2 : hl;     // <= 4
        const int nx = x4 ? (wl + 3) >> 2 : wl;     // <= 4
        const int ystep = y4 ? 4 : 1, xstep = x4 ? 4 : 1;
        const int ycl = y4 ? ye - 4 : ye - 1;
        const int xcl = x4 ? xe - 4 : xe - 1;
        const float* tb = y4 ? (x4 ? s4xy : s4y) : (x4 ? s4x : fm);
        const float* tbb = tb + (size_t)b * H * W * C + lane * 4;

        // x-span byte offsets (uniform)
        const int xo0 = min(xs,             xcl) * C;
        const int xo1 = min(xs + xstep,     xcl) * C;
        const int xo2 = min(xs + 2 * xstep, xcl) * C;
        const int xo3 = min(xs + 3 * xstep, xcl) * C;

        #pragma unroll
        for (int ky = 0; ky < 4; ++ky) {
            if (ky < ny) {                           // wave-uniform guard
                const int y = min(ys + ystep * ky, ycl);
                const float* rowp = tbb + (size_t)y * (W * C);
                a0 = vmax4(a0, *(const f32x4*)(rowp + xo0));
                if (nx > 1) a1 = vmax4(a1, *(const f32x4*)(rowp + xo1));
                if (nx > 2) a2 = vmax4(a2, *(const f32x4*)(rowp + xo2));
                if (nx > 3) a3 = vmax4(a3, *(const f32x4*)(rowp + xo3));
            }
        }
    }
    const f32x4 acc = vmax4(vmax4(a0, a1), vmax4(a2, a3));

    size_t o = ((((size_t)b * R + r) * PH + i) * PW + j) * C + (size_t)lane * 4;
    __builtin_nontemporal_store(acc, reinterpret_cast<f32x4*>(out + o));
}

// ---- verified fallback (R5 kernel) if ws too small ----
__global__ __launch_bounds__(256) void roi_pool_direct(
    const float* __restrict__ fm, const float* __restrict__ rois,
    float* __restrict__ out, int R)
{
    const int lane = threadIdx.x & 63;
    const int wave = __builtin_amdgcn_readfirstlane(threadIdx.x >> 6);
    const int b = blockIdx.x & 1;
    int m = (blockIdx.x >> 1) * 4 + wave;
    int j = m % PW; m /= PW;
    int i = m % PH; m /= PH;
    int r = m;

    const float* roi = rois + ((size_t)b * R + r) * 4;
    int h0 = (int)((float)H * roi[0]);
    int w0 = (int)((float)W * roi[1]);
    int h1 = (int)((float)H * roi[2]);
    int w1 = (int)((float)W * roi[3]);
    int hs = (h1 - h0) / PH;
    int ws = (w1 - w0) / PW;

    int ys, ye, xs, xe;
    if (hs > 0) { ys = h0 + i * hs; ye = (i < PH - 1) ? (ys + hs) : h1; }
    else        { ys = h0;          ye = (i == PH - 1) ? h1 : h0; }
    if (ws > 0) { xs = w0 + j * ws; xe = (j < PW - 1) ? (xs + ws) : w1; }
    else        { xs = w0;          xe = (j == PW - 1) ? w1 : w0; }
    ys = __builtin_amdgcn_readfirstlane(max(ys, 0));
    ye = __builtin_amdgcn_readfirstlane(min(ye, H));
    xs = __builtin_amdgcn_readfirstlane(max(xs, 0));
    xe = __builtin_amdgcn_readfirstlane(min(xe, W));

    const f32x4 NEG = {-FLT_MAX, -FLT_MAX, -FLT_MAX, -FLT_MAX};
    f32x4 a0 = NEG, a1 = NEG, a2 = NEG, a3 = NEG;
    const float* fmb = fm + (size_t)b * (H * W * C);
    const int lo = lane * 4;

    for (int y = ys; y < ye; y += 2) {
        const int y1 = min(y + 1, ye - 1);
        const int ro0 = y  * (W * C);
        const int ro1 = y1 * (W * C);
        for (int x = xs; x < xe; x += 2) {
            const int x1 = min(x + 1, xe - 1);
            a0 = vmax4(a0, *(const f32x4*)(fmb + ro0 + x  * C + lo));
            a1 = vmax4(a1, *(const f32x4*)(fmb + ro0 + x1 * C + lo));
            a2 = vmax4(a2, *(const f32x4*)(fmb + ro1 + x  * C + lo));
            a3 = vmax4(a3, *(const f32x4*)(fmb + ro1 + x1 * C + lo));
        }
    }
    f32x4 acc = vmax4(vmax4(a0, a1), vmax4(a2, a3));
    size_t o = ((((size_t)b * R + r) * PH + i) * PW + j) * C + (size_t)lo;
    __builtin_nontemporal_store(acc, reinterpret_cast<f32x4*>(out + o));
}

extern "C" void kernel_launch(void* const* d_in, const int* in_sizes, int n_in,
                              void* d_out, int out_size, void* d_ws, size_t ws_size,
                              hipStream_t stream) {
    const float* fm   = (const float*)d_in[0];
    const float* rois = (const float*)d_in[1];
    float* out = (float*)d_out;

    const int B = in_sizes[0] / (H * W * C);        // = 2
    const int R = in_sizes[1] / (B * 4);            // = 256

    const size_t tbl = (size_t)B * H * W * C;       // floats per table
    const size_t need = 3 * tbl * sizeof(float);    // 24 MB for B=2
    const int qblocks = B * (R * PH * PW / 4);      // 6272

    if (B == 2 && ws_size >= need) {
        float* s4x  = (float*)d_ws;
        float* s4y  = s4x + tbl;
        float* s4xy = s4y + tbl;
        const int bblocks = B * W * (H / 4);        // 2048
        build_tables<<<bblocks, 256, 0, stream>>>(fm, s4x, s4y, s4xy);
        roi_pool_q  <<<qblocks, 256, 0, stream>>>(fm, rois, s4x, s4y, s4xy, out, R);
    } else {
        roi_pool_direct<<<qblocks, 256, 0, stream>>>(fm, rois, out, R);
    }
}